// Round 2
// baseline (53.263 us; speedup 1.0000x reference)
//
#include <hip/hip_runtime.h>

// Analytical reduction of the 12-qubit circuit:
//   RY on |0..0> -> product state with independent bits b_q ~ Bern(sin^2(theta_q/2))
//   CNOT chain   -> basis permutation: bit'_i = b_0 ^ ... ^ b_i (prefix XOR)
//   <Z_i> = E[(-1)^(b_0^...^b_i)] = prod_{j<=i} E[(-1)^{b_j}]
//         = prod_{j<=i} cos(pi * clip(in[b][j], 0, 1))
// One thread per batch row; float4 loads/stores (row = 48 B, 16B-aligned).

#define NQ 12

__global__ __launch_bounds__(256) void quantum_layer_kernel(
    const float* __restrict__ in, float* __restrict__ out, int batch) {
    for (int b = blockIdx.x * blockDim.x + threadIdx.x; b < batch;
         b += gridDim.x * blockDim.x) {
        const float4* inv = reinterpret_cast<const float4*>(in + (size_t)b * NQ);
        float4 x0 = inv[0];
        float4 x1 = inv[1];
        float4 x2 = inv[2];
        float v[NQ] = {x0.x, x0.y, x0.z, x0.w,
                       x1.x, x1.y, x1.z, x1.w,
                       x2.x, x2.y, x2.z, x2.w};

        float o[NQ];
        float prod = 1.0f;
#pragma unroll
        for (int q = 0; q < NQ; ++q) {
            float t = fminf(fmaxf(v[q], 0.0f), 1.0f);
            prod *= cospif(t);      // cos(pi * t), exact pi scaling
            o[q] = prod;
        }

        float4* outv = reinterpret_cast<float4*>(out + (size_t)b * NQ);
        outv[0] = make_float4(o[0], o[1], o[2],  o[3]);
        outv[1] = make_float4(o[4], o[5], o[6],  o[7]);
        outv[2] = make_float4(o[8], o[9], o[10], o[11]);
    }
}

extern "C" void kernel_launch(void* const* d_in, const int* in_sizes, int n_in,
                              void* d_out, int out_size, void* d_ws, size_t ws_size,
                              hipStream_t stream) {
    const float* in = (const float*)d_in[0];
    float* out = (float*)d_out;
    int batch = in_sizes[0] / NQ;   // 16384

    const int block = 256;
    int grid = (batch + block - 1) / block;   // 64 blocks for 16384 rows
    quantum_layer_kernel<<<grid, block, 0, stream>>>(in, out, batch);
}

// Round 3
// 52.516 us; speedup vs baseline: 1.0142x; 1.0142x over previous
//
#include <hip/hip_runtime.h>

// Analytical reduction of the 12-qubit circuit:
//   RY on |0..0> -> product state, bits b_q ~ Bern(sin^2(theta_q/2))
//   CNOT chain   -> basis permutation: bit'_i = b_0 ^ ... ^ b_i (prefix XOR)
//   <Z_i> = prod_{j<=i} cos(pi * clip(in[b][j], 0, 1))
//
// cos(pi*t) via v_cos_f32: HW computes cos(x * 2pi), so pass x = t/2.
// t/2 in [0, 0.5] -> no range reduction needed. ~2 VALU ops per qubit
// vs OCML cospif's full reduction path.

#define NQ 12

__global__ __launch_bounds__(128) void quantum_layer_kernel(
    const float* __restrict__ in, float* __restrict__ out, int batch) {
    for (int b = blockIdx.x * blockDim.x + threadIdx.x; b < batch;
         b += gridDim.x * blockDim.x) {
        const float4* inv = reinterpret_cast<const float4*>(in + (size_t)b * NQ);
        float4 x0 = inv[0];
        float4 x1 = inv[1];
        float4 x2 = inv[2];
        float v[NQ] = {x0.x, x0.y, x0.z, x0.w,
                       x1.x, x1.y, x1.z, x1.w,
                       x2.x, x2.y, x2.z, x2.w};

        float c[NQ];
#pragma unroll
        for (int q = 0; q < NQ; ++q) {
            float t = fminf(fmaxf(v[q], 0.0f), 1.0f);   // clamp -> v_med3
#if __has_builtin(__builtin_amdgcn_cosf)
            c[q] = __builtin_amdgcn_cosf(0.5f * t);     // cos(2pi * t/2) = cos(pi*t)
#else
            c[q] = __cosf(3.14159265358979f * t);
#endif
        }

        float o[NQ];
        float prod = 1.0f;
#pragma unroll
        for (int q = 0; q < NQ; ++q) {
            prod *= c[q];
            o[q] = prod;
        }

        float4* outv = reinterpret_cast<float4*>(out + (size_t)b * NQ);
        outv[0] = make_float4(o[0], o[1], o[2],  o[3]);
        outv[1] = make_float4(o[4], o[5], o[6],  o[7]);
        outv[2] = make_float4(o[8], o[9], o[10], o[11]);
    }
}

extern "C" void kernel_launch(void* const* d_in, const int* in_sizes, int n_in,
                              void* d_out, int out_size, void* d_ws, size_t ws_size,
                              hipStream_t stream) {
    const float* in = (const float*)d_in[0];
    float* out = (float*)d_out;
    int batch = in_sizes[0] / NQ;   // 16384

    const int block = 128;
    int grid = (batch + block - 1) / block;   // 128 blocks -> 128 CUs
    quantum_layer_kernel<<<grid, block, 0, stream>>>(in, out, batch);
}